// Round 2
// baseline (190.485 us; speedup 1.0000x reference)
//
#include <hip/hip_runtime.h>
#include <stdint.h>

// ---------------------------------------------------------------------------
// MultiHeadAttention forward, MI355X/gfx950.  Round 11.
// fp32 I/O, bf16 MFMA compute. B=2 S=2048 D=1024 H=16 HD=64. M=4096.
// R11 vs R10 (NaN): R10's reduce combines used inline-asm
//   v_permlane32_swap with two tied "+v" operands holding the SAME value;
//   LLVM coalesced them into one VGPR -> self-swap -> halves never combined
//   -> under-estimated row max -> exp2 overflow -> inf*0 = NaN.
// Fix: cross-half max/sum combines via __shfl_xor(x,32) (known-correct);
//   P-frag half-exchange via __builtin_amdgcn_permlane32_swap (compiler-
//   modeled, distinct result regs guaranteed). No other changes.
// attn design (R10): mfma_f32_32x32x16_bf16, register-resident P:
//   - S^T = mfma32(K, Q^T): col=q=l31, row=key=(reg&3)+8*(reg>>2)+4*hi.
//   - softmax in-register; PV A-frags via permlane32_swap (2/frag).
//   - K [128][64] / V^T [64][128] XOR-swizzled (chunk ^= row&7), staged via
//     global_load_lds w/ pre-swizzled source, double-buffered, counted
//     s_waitcnt vmcnt(8) + raw s_barrier (prefetch never drained).
//   - defer-max (THR=44 raw ~ 8 in exp2 domain): O-rescale usually skipped.
// Pipeline: cvt_all -> gemm_qkv_a -> attn -> gemm_out_m.
// MFMA layouts [m89/m74-verified]:
//   16x16x32: A[m=l15][k=quad*8+j]; B[n=l15][k=quad*8+j]; C col=l15,row=quad*4+r
//   32x32x16: A[m=l31][k=hi*8+j];   B[n=l31][k=hi*8+j];   C col=l31,
//             row=(reg&3)+8*(reg>>2)+4*hi
// permlane32_swap: ret[0] = {x_lo|y_lo}, ret[1] = {x_hi|y_hi}.
// ---------------------------------------------------------------------------

typedef __bf16 bf16_t;
typedef __bf16 bf16x8 __attribute__((ext_vector_type(8)));
typedef float  f32x4  __attribute__((ext_vector_type(4)));
typedef float  f32x16 __attribute__((ext_vector_type(16)));
typedef uint32_t u32x4 __attribute__((ext_vector_type(4)));
typedef uint32_t u32x2 __attribute__((ext_vector_type(2)));

#define MFMA16(A, B, C) __builtin_amdgcn_mfma_f32_16x16x32_bf16(A, B, C, 0, 0, 0)
#define MFMA32(A, B, C) __builtin_amdgcn_mfma_f32_32x32x16_bf16(A, B, C, 0, 0, 0)

__device__ __forceinline__ void async_ld16(const bf16_t* g, bf16_t* l) {
  __builtin_amdgcn_global_load_lds(
      (const __attribute__((address_space(1))) void*)g,
      (__attribute__((address_space(3))) void*)l, 16, 0, 0);
}

// ret[0] = {x[0:31] | y[0:31]},  ret[1] = {x[32:63] | y[32:63]}
__device__ __forceinline__ u32x2 pl32swap(uint32_t x, uint32_t y) {
  return __builtin_amdgcn_permlane32_swap(x, y, false, false);
}

__device__ __forceinline__ u32x4 ld8(const float* p) {
  const float4 a = *(const float4*)p;
  const float4 b = *(const float4*)(p + 4);
  union { u32x4 v; bf16_t h[8]; } r;
  r.h[0] = (bf16_t)a.x; r.h[1] = (bf16_t)a.y;
  r.h[2] = (bf16_t)a.z; r.h[3] = (bf16_t)a.w;
  r.h[4] = (bf16_t)b.x; r.h[5] = (bf16_t)b.y;
  r.h[6] = (bf16_t)b.z; r.h[7] = (bf16_t)b.w;
  return r.v;
}

// --- fp32 -> bf16 converter: y=0 x (4096 blks); y=1..3 Wq/Wk/Wv (1024) -----
__global__ __launch_bounds__(256) void cvt_all(
    const float* __restrict__ sx, const float* __restrict__ s1,
    const float* __restrict__ s2, const float* __restrict__ s3,
    bf16_t* __restrict__ dx, bf16_t* __restrict__ d1,
    bf16_t* __restrict__ d2, bf16_t* __restrict__ d3) {
  const int y = blockIdx.y;
  if (y != 0 && blockIdx.x >= 1024) return;
  const int i4 = (blockIdx.x * 256 + threadIdx.x) * 4;
  const float* s = (y == 0) ? sx : (y == 1) ? s1 : (y == 2) ? s2 : s3;
  bf16_t*      d = (y == 0) ? dx : (y == 1) ? d1 : (y == 2) ? d2 : d3;
  const float4 v = *(const float4*)(s + i4);
  union { uint64_t u; bf16_t h[4]; } pk;
  pk.h[0] = (bf16_t)v.x; pk.h[1] = (bf16_t)v.y;
  pk.h[2] = (bf16_t)v.z; pk.h[3] = (bf16_t)v.w;
  *(uint64_t*)(d + i4) = pk.u;
}

// ---------------------------------------------------------------------------
// Async-staged bf16 GEMM (128x128, BK=64): QKV projections.
// mode 0: Q/K [B,H,S,64]; mode 1: V^T [B,H,64,S].
// ---------------------------------------------------------------------------
__global__ __launch_bounds__(256, 2) void gemm_qkv_a(
    const bf16_t* __restrict__ X,  const bf16_t* __restrict__ Wq,
    const bf16_t* __restrict__ Wk, const bf16_t* __restrict__ Wv,
    bf16_t* __restrict__ Q, bf16_t* __restrict__ K, bf16_t* __restrict__ V) {
  const int z = blockIdx.z;
  const bf16_t* W = (z == 0) ? Wq : (z == 1) ? Wk : Wv;
  bf16_t*       D = (z == 0) ? Q  : (z == 1) ? K  : V;
  const int mode = (z == 2) ? 1 : 0;

  __shared__ __align__(16) bf16_t As[128 * 64];
  __shared__ __align__(16) bf16_t Bs[128 * 64];

  const int tid  = threadIdx.x;
  const int lane = tid & 63;
  const int w    = tid >> 6;
  const int quad = lane >> 4;
  const int l15  = lane & 15;
  const int bm   = blockIdx.y * 128;
  const int bn   = blockIdx.x * 128;
  const int wm   = (w >> 1) * 64;
  const int wn   = (w & 1) * 64;
  const int sr   = lane >> 3;
  const int sc   = lane & 7;

  f32x4 acc[4][4] = {};

  for (int k0 = 0; k0 < 1024; k0 += 64) {
#pragma unroll
    for (int j = 0; j < 4; ++j) {
      const int r0 = w * 32 + j * 8;
      const int r  = r0 + sr;
      const int c  = sc ^ (r & 7);
      async_ld16(X + (size_t)(bm + r) * 1024 + k0 + c * 8, &As[r0 * 64]);
      async_ld16(W + (size_t)(bn + r) * 1024 + k0 + c * 8, &Bs[r0 * 64]);
    }
    __syncthreads();
#pragma unroll
    for (int kk = 0; kk < 64; kk += 32) {
      const int ck = (kk >> 3) + quad;
      bf16x8 aF[4], bF[4];
#pragma unroll
      for (int mt = 0; mt < 4; ++mt) {
        const int r = wm + mt * 16 + l15;
        aF[mt] = *(const bf16x8*)&As[r * 64 + (ck ^ (r & 7)) * 8];
      }
#pragma unroll
      for (int nt = 0; nt < 4; ++nt) {
        const int r = wn + nt * 16 + l15;
        bF[nt] = *(const bf16x8*)&Bs[r * 64 + (ck ^ (r & 7)) * 8];
      }
#pragma unroll
      for (int mt = 0; mt < 4; ++mt)
#pragma unroll
        for (int nt = 0; nt < 4; ++nt)
          acc[mt][nt] = MFMA16(aF[mt], bF[nt], acc[mt][nt]);
    }
    __syncthreads();
  }

#pragma unroll
  for (int mt = 0; mt < 4; ++mt) {
#pragma unroll
    for (int nt = 0; nt < 4; ++nt) {
      const int n  = bn + wn + nt * 16 + l15;
      const int mb = bm + wm + mt * 16 + quad * 4;
      const int h = n >> 6, hd = n & 63;
      if (mode == 0) {               // Q/K: [B,H,S,64]
#pragma unroll
        for (int r = 0; r < 4; ++r) {
          const int m = mb + r;
          const int b = m >> 11, s = m & 2047;
          D[(size_t)b * 2097152 + (size_t)h * 131072 + (size_t)s * 64 + hd] =
              (bf16_t)acc[mt][nt][r];
        }
      } else {                       // V^T: [B,H,64,S]; 4 consecutive tokens
        const int b = mb >> 11, s0 = mb & 2047;
        union { uint64_t u; bf16_t h4[4]; } pk;
#pragma unroll
        for (int r = 0; r < 4; ++r) pk.h4[r] = (bf16_t)acc[mt][nt][r];
        *(uint64_t*)(D + (size_t)b * 2097152 + (size_t)h * 131072 +
                     (size_t)hd * 2048 + s0) = pk.u;
      }
    }
  }
}

// ---------------------------------------------------------------------------
// gemm_out: 64x128 tile, BK=64, grid (8,64)=512 blocks (2/CU overlap).
// A = ctx bf16 (async LDS staging); B = Wo FP32 from d_in (register cvt ->
// swizzled LDS writes). out = ctx @ Wo^T + bo, FP32.
// ---------------------------------------------------------------------------
__global__ __launch_bounds__(256, 2) void gemm_out_m(
    const bf16_t* __restrict__ ctx, const float* __restrict__ Wo,
    float* __restrict__ out, const float* __restrict__ bo) {
  __shared__ __align__(16) bf16_t As[64 * 64];
  __shared__ __align__(16) bf16_t Bs[128 * 64];

  const int tid  = threadIdx.x;
  const int lane = tid & 63;
  const int w    = tid >> 6;
  const int quad = lane >> 4;
  const int l15  = lane & 15;
  const int bm   = blockIdx.y * 64;
  const int bn   = blockIdx.x * 128;
  const int wm   = (w >> 1) * 32;
  const int wn   = (w & 1) * 64;
  const int sr   = lane >> 3;
  const int sc   = lane & 7;
  const int srow = tid >> 3;        // 0..31
  const int schk = tid & 7;

  f32x4 acc[2][4] = {};

  for (int k0 = 0; k0 < 1024; k0 += 64) {
    // A: async bf16 staging (2 row-groups per wave)
#pragma unroll
    for (int j = 0; j < 2; ++j) {
      const int r0 = w * 16 + j * 8;
      const int r  = r0 + sr;
      const int c  = sc ^ (r & 7);
      async_ld16(ctx + (size_t)(bm + r) * 1024 + k0 + c * 8, &As[r0 * 64]);
    }
    // B: fp32 global -> regs (cvt) -> swizzled LDS (Bs free since loop-end barrier)
    u32x4 rb[4];
#pragma unroll
    for (int s2 = 0; s2 < 4; ++s2) {
      const int r = srow + s2 * 32;
      rb[s2] = ld8(Wo + (size_t)(bn + r) * 1024 + k0 + schk * 8);
    }
#pragma unroll
    for (int s2 = 0; s2 < 4; ++s2) {
      const int r = srow + s2 * 32;
      *(u32x4*)&Bs[r * 64 + ((schk ^ (r & 7)) * 8)] = rb[s2];
    }
    __syncthreads();    // drains async A (vmcnt) + B ds_writes (lgkmcnt)
#pragma unroll
    for (int kk = 0; kk < 64; kk += 32) {
      const int ck = (kk >> 3) + quad;
      bf16x8 aF[2], bF[4];
#pragma unroll
      for (int mt = 0; mt < 2; ++mt) {
        const int r = wm + mt * 16 + l15;
        aF[mt] = *(const bf16x8*)&As[r * 64 + (ck ^ (r & 7)) * 8];
      }
#pragma unroll
      for (int nt = 0; nt < 4; ++nt) {
        const int r = wn + nt * 16 + l15;
        bF[nt] = *(const bf16x8*)&Bs[r * 64 + (ck ^ (r & 7)) * 8];
      }
#pragma unroll
      for (int mt = 0; mt < 2; ++mt)
#pragma unroll
        for (int nt = 0; nt < 4; ++nt)
          acc[mt][nt] = MFMA16(aF[mt], bF[nt], acc[mt][nt]);
    }
    __syncthreads();    // all reads done before next staging overwrites
  }

#pragma unroll
  for (int mt = 0; mt < 2; ++mt) {
#pragma unroll
    for (int nt = 0; nt < 4; ++nt) {
      const int n  = bn + wn + nt * 16 + l15;
      const int mb = bm + wm + mt * 16 + quad * 4;
      const float bv = bo[n];
#pragma unroll
      for (int r = 0; r < 4; ++r)
        out[(size_t)(mb + r) * 1024 + n] = acc[mt][nt][r] + bv;
    }
  }
}

// ---------------------------------------------------------------------------
// Flash-style causal attention, 32x32 MFMA, register-resident P.
// Grid (16,16,2), 256 thr.  qt remap: z==0 -> x, z==1 -> 15-x (z-pairing).
// Q,K: [B,H,S,64] bf16; V^T: [B,H,64,S] bf16; ctx: [B,S,1024] bf16.
// Per wave: 32 q-rows (q = l31), KVBLK=128 per iter, double-buffered K/V in
// LDS (XOR swizzle chunk^=row&7) via global_load_lds w/ pre-swizzled source.
// ---------------------------------------------------------------------------
__global__ __launch_bounds__(256, 2) void attn(
    const bf16_t* __restrict__ Qw, const bf16_t* __restrict__ Kw,
    const bf16_t* __restrict__ Vw, bf16_t* __restrict__ ctx) {
  __shared__ __align__(16) bf16_t Kb[2][128 * 64];   // [key][d]
  __shared__ __align__(16) bf16_t Vb[2][64 * 128];   // [hd][key]

  const int tid  = threadIdx.x;
  const int lane = tid & 63;
  const int w    = tid >> 6;
  const int l31  = lane & 31;
  const int hi   = lane >> 5;
  const int b    = blockIdx.z;
  const int qt   = (b == 0) ? blockIdx.x : 15 - blockIdx.x;
  const int h    = blockIdx.y;
  const size_t bh = (size_t)(b * 16 + h) * (size_t)(2048 * 64);
  const bf16_t* Qh = Qw + bh;
  const bf16_t* Kh = Kw + bh;
  const bf16_t* Vh = Vw + bh;          // [64][2048]

  // --- Q fragments straight from global: B-frag B[k=d][n=q=l31] ---
  bf16x8 qF[4];
  {
    const bf16_t* qrow = Qh + (size_t)(qt * 128 + w * 32 + l31) * 64 + hi * 8;
#pragma unroll
    for (int t2 = 0; t2 < 4; ++t2) qF[t2] = *(const bf16x8*)(qrow + t2 * 16);
  }

  const int krl = lane >> 3, kcl = lane & 7;    // K staging: 8 rows/issue
  const int vrl = lane >> 4, vcl = lane & 15;   // V staging: 4 rows/issue

  // --- prologue: stage tile 0 into buf 0 (pre-swizzled global source) ---
  {
#pragma unroll
    for (int j = 0; j < 4; ++j) {
      const int r0 = w * 32 + j * 8;
      const int r  = r0 + krl;
      async_ld16(Kh + (size_t)r * 64 + (kcl ^ (r & 7)) * 8, &Kb[0][r0 * 64]);
    }
#pragma unroll
    for (int j = 0; j < 4; ++j) {
      const int r0 = w * 16 + j * 4;
      const int r  = r0 + vrl;
      async_ld16(Vh + (size_t)r * 2048 + (vcl ^ (r & 7)) * 8, &Vb[0][r0 * 128]);
    }
  }

  f32x16 O[2] = {};
  float mrow = -1e30f, lrow = 0.f;
  const float sc_log2 = 0.125f * 1.44269504088896340736f;  // 1/sqrt(64)*log2e
  const float DTHR = 44.0f;            // ~8/sc_log2: defer-max headroom, p<=256

  for (int kt = 0; kt <= qt; ++kt) {
    const int cur = kt & 1;
    // C0: all waves finished reading buf[cur^1] (iter kt-1) before overwrite
    asm volatile("" ::: "memory");
    __builtin_amdgcn_s_barrier();
    asm volatile("" ::: "memory");
    if (kt < qt) {
      const int kn = kt + 1;
#pragma unroll
      for (int j = 0; j < 4; ++j) {
        const int r0 = w * 32 + j * 8;
        const int r  = r0 + krl;
        async_ld16(Kh + (size_t)(kn * 128 + r) * 64 + (kcl ^ (r & 7)) * 8,
                   &Kb[cur ^ 1][r0 * 64]);
      }
#pragma unroll
      for (int j = 0; j < 4; ++j) {
        const int r0 = w * 16 + j * 4;
        const int r  = r0 + vrl;
        async_ld16(Vh + (size_t)r * 2048 + kn * 128 + (vcl ^ (r & 7)) * 8,
                   &Vb[cur ^ 1][r0 * 128]);
      }
      // 8 issues in flight for tile kn; wait for tile kt's 8 to land
      asm volatile("s_waitcnt vmcnt(8)" ::: "memory");
    } else {
      asm volatile("s_waitcnt vmcnt(0)" ::: "memory");
    }
    __builtin_amdgcn_s_barrier();      // C1: tile kt resident in buf[cur]
    asm volatile("" ::: "memory");

    // --- S^T = K Q^T (32x32x16): col=q=l31, row=key=(reg&3)+8*(reg>>2)+4hi ---
    f32x16 St[4] = {};
#pragma unroll
    for (int c = 0; c < 4; ++c) {
      const int kr = c * 32 + l31;
      const bf16_t* kbase = &Kb[cur][kr * 64];
      const int sw = kr & 7;
#pragma unroll
      for (int t2 = 0; t2 < 4; ++t2) {
        const bf16x8 kF = *(const bf16x8*)(kbase + (((t2 << 1) | hi) ^ sw) * 8);
        St[c] = MFMA32(kF, qF[t2], St[c]);
      }
    }

    // --- causal mask on the diagonal tile (wave-uniform branch) ---
    if (kt == qt) {
#pragma unroll
      for (int c = 0; c < 4; ++c)
#pragma unroll
        for (int g = 0; g < 4; ++g)
#pragma unroll
          for (int r2 = 0; r2 < 4; ++r2)
            if (c * 32 + g * 8 + hi * 4 + r2 > w * 32 + l31)
              St[c][g * 4 + r2] = -1e30f;
    }

    // --- row max: own 64 regs, then cross-half combine (lane l <-> l+32) ---
    float mx = -1e30f;
#pragma unroll
    for (int c = 0; c < 4; ++c)
#pragma unroll
      for (int rg = 0; rg < 16; ++rg) mx = fmaxf(mx, St[c][rg]);
    mx = fmaxf(mx, __shfl_xor(mx, 32));

    // --- defer-max: rescale O only when the running max actually grows ---
    float alpha = 1.f;
    if (!__all(mx - mrow <= DTHR)) {
      const float mnew = fmaxf(mrow, mx);
      alpha = exp2f((mrow - mnew) * sc_log2);
      mrow = mnew;
#pragma unroll
      for (int g = 0; g < 4; ++g)
#pragma unroll
        for (int r2 = 0; r2 < 4; ++r2) {
          const float a = __shfl(alpha, g * 8 + hi * 4 + r2);
          O[0][g * 4 + r2] *= a;
          O[1][g * 4 + r2] *= a;
        }
    }

    // --- exp, pack to bf16, permlane into PV A-frags, PV MFMA ---
    const float mb = mrow * sc_log2;
    float rs = 0.f;
#pragma unroll
    for (int c = 0; c < 4; ++c) {
      uint32_t pk0[4], pk1[4];     // [g]: keys 8g+4hi+{0,1} / +{2,3}
#pragma unroll
      for (int g = 0; g < 4; ++g) {
        const float p0 = exp2f(St[c][g * 4 + 0] * sc_log2 - mb);
        const float p1 = exp2f(St[c][g * 4 + 1] * sc_log2 - mb);
        const float p2 = exp2f(St[c][g * 4 + 2] * sc_log2 - mb);
        const float p3 = exp2f(St[c][g * 4 + 3] * sc_log2 - mb);
        rs += (p0 + p1) + (p2 + p3);
        union { uint32_t u; bf16_t h2[2]; } a0, a1;
        a0.h2[0] = (bf16_t)p0; a0.h2[1] = (bf16_t)p1;
        a1.h2[0] = (bf16_t)p2; a1.h2[1] = (bf16_t)p3;
        pk0[g] = a0.u; pk1[g] = a1.u;
      }
#pragma unroll
      for (int tl = 0; tl < 2; ++tl) {
        // frag[t] (t = 2c+tl) holds P[q=l31][16t + 8hi + (0..7)]:
        //   words {0,2} = swap(pk0[2tl], pk0[2tl+1]); {1,3} = swap(pk1[...])
        const u32x2 s0 = pl32swap(pk0[2 * tl], pk0[2 * tl + 1]);
        const u32x2 s1 = pl32swap(pk1[2 * tl], pk1[2 * tl + 1]);
        union { u32x4 u4; bf16x8 h8; } fr;
        fr.u4 = u32x4{s0[0], s1[0], s0[1], s1[1]};
        const int t = c * 2 + tl;
#pragma unroll
        for (int nb = 0; nb < 2; ++nb) {
          const int vr = nb * 32 + l31;
          const bf16x8 vF = *(const bf16x8*)
              &Vb[cur][vr * 128 + ((((t << 1) | hi) ^ (vr & 7)) * 8)];
          O[nb] = MFMA32(fr.h8, vF, O[nb]);
        }
      }
    }
    rs += __shfl_xor(rs, 32);          // cross-half row-sum combine
    lrow = lrow * alpha + rs;
  }

  // --- epilogue: normalize (lrow broadcast col->row layout), store ctx ---
#pragma unroll
  for (int g = 0; g < 4; ++g) {
#pragma unroll
    for (int r2 = 0; r2 < 4; ++r2) {
      const int qrow = g * 8 + hi * 4 + r2;
      const float lr = __shfl(lrow, qrow);
      const float iv = 1.f / lr;
      const int s = qt * 128 + w * 32 + qrow;
      bf16_t* crow = ctx + (size_t)(b * 2048 + s) * 1024 + h * 64 + l31;
      crow[0]  = (bf16_t)(O[0][g * 4 + r2] * iv);
      crow[32] = (bf16_t)(O[1][g * 4 + r2] * iv);
    }
  }
}

// ---------------------------------------------------------------------------
extern "C" void kernel_launch(void* const* d_in, const int* in_sizes, int n_in,
                              void* d_out, int out_size, void* d_ws, size_t ws_size,
                              hipStream_t stream) {
  const float* x  = (const float*)d_in[0];
  const float* Wq = (const float*)d_in[1];
  const float* Wk = (const float*)d_in[2];
  const float* Wv = (const float*)d_in[3];
  const float* Wo = (const float*)d_in[4];
  const float* bo = (const float*)d_in[5];

  bf16_t* ws   = (bf16_t*)d_ws;       // ws: exactly 32 MB used
  bf16_t* Qw   = ws;                  // 4M bf16 elems each
  bf16_t* Kw   = ws + 4194304;
  bf16_t* Vw   = ws + 8388608;        // [B,H,64,S]
  bf16_t* ctxw = ws + 12582912;

  bf16_t* dscr = (bf16_t*)d_out;      // d_out as bf16 scratch (14 of 16 MB)
  bf16_t* xb   = dscr;                // 8 MB
  bf16_t* Wqb  = dscr + 4194304;      // 2 MB each
  bf16_t* Wkb  = dscr + 5242880;
  bf16_t* Wvb  = dscr + 6291456;      // ends at 14 MB
  float*  out  = (float*)d_out;       // final fp32 output overwrites scratch

  dim3 blk(256);
  cvt_all<<<dim3(4096, 4), blk, 0, stream>>>(x, Wq, Wk, Wv, xb, Wqb, Wkb, Wvb);
  gemm_qkv_a<<<dim3(8, 32, 3), blk, 0, stream>>>(xb, Wqb, Wkb, Wvb, Qw, Kw, Vw);
  attn<<<dim3(16, 16, 2), blk, 0, stream>>>(Qw, Kw, Vw, ctxw);
  gemm_out_m<<<dim3(8, 64), blk, 0, stream>>>(ctxw, Wo, out, bo);
}

// Round 3
// 187.311 us; speedup vs baseline: 1.0169x; 1.0169x over previous
//
#include <hip/hip_runtime.h>
#include <stdint.h>

// ---------------------------------------------------------------------------
// MultiHeadAttention forward, MI355X/gfx950.  Round 12.
// fp32 I/O, bf16 MFMA compute. B=2 S=2048 D=1024 H=16 HD=64. M=4096.
// R12 vs R11 (190.5 us; attn 70.4 us regressed) / R9 (187.1; attn 60.2):
//  attn is occupancy-bound, not pipe-bound (VALU 39 + Mfma 11 ~= 50% issue
//  at 2 waves/SIMD; R8 lesson: solo 11.8K vs dual 8.3K cyc/iter).
//  -> REVERT to R9's verified 16x16 structure, HALVED tiles: 64 q-rows,
//     KV=64, LDS 3x64x72x2 = 27648 B -> 4 blocks/CU, launch_bounds(256,4).
//     Grid (32,16,2)=1024 blocks = exactly 4/CU.
//  -> balance: co-resident ids {c,c+256,c+512,c+768} differ in (y>>3, z);
//     r64 = {x, 31-x, (x+16)&31, (15-x)&31} by u=(z<<1)|(y>>3): every CU
//     gets exactly 66 block-iters (bijective per (h,b)).
//  -> + T5 setprio around MFMA clusters (m191 attn-verified);
//     + defer-max (validated in R11 run, absmax 0.0156).
// Pipeline: cvt_all -> gemm_qkv_a -> attn -> gemm_out_m (others unchanged).
// MFMA 16x16x32 layouts [m89-verified]:
//   A[m=l15][k=quad*8+j]; B[n=l15][k=quad*8+j]; C/D col=l15, row=quad*4+r.
// ---------------------------------------------------------------------------

typedef __bf16 bf16_t;
typedef __bf16 bf16x8 __attribute__((ext_vector_type(8)));
typedef float  f32x4  __attribute__((ext_vector_type(4)));
typedef uint32_t u32x4 __attribute__((ext_vector_type(4)));

#define MFMA16(A, B, C) __builtin_amdgcn_mfma_f32_16x16x32_bf16(A, B, C, 0, 0, 0)

__device__ __forceinline__ void async_ld16(const bf16_t* g, bf16_t* l) {
  __builtin_amdgcn_global_load_lds(
      (const __attribute__((address_space(1))) void*)g,
      (__attribute__((address_space(3))) void*)l, 16, 0, 0);
}

__device__ __forceinline__ u32x4 ld8(const float* p) {
  const float4 a = *(const float4*)p;
  const float4 b = *(const float4*)(p + 4);
  union { u32x4 v; bf16_t h[8]; } r;
  r.h[0] = (bf16_t)a.x; r.h[1] = (bf16_t)a.y;
  r.h[2] = (bf16_t)a.z; r.h[3] = (bf16_t)a.w;
  r.h[4] = (bf16_t)b.x; r.h[5] = (bf16_t)b.y;
  r.h[6] = (bf16_t)b.z; r.h[7] = (bf16_t)b.w;
  return r.v;
}

// --- fp32 -> bf16 converter: y=0 x (4096 blks); y=1..3 Wq/Wk/Wv (1024) -----
__global__ __launch_bounds__(256) void cvt_all(
    const float* __restrict__ sx, const float* __restrict__ s1,
    const float* __restrict__ s2, const float* __restrict__ s3,
    bf16_t* __restrict__ dx, bf16_t* __restrict__ d1,
    bf16_t* __restrict__ d2, bf16_t* __restrict__ d3) {
  const int y = blockIdx.y;
  if (y != 0 && blockIdx.x >= 1024) return;
  const int i4 = (blockIdx.x * 256 + threadIdx.x) * 4;
  const float* s = (y == 0) ? sx : (y == 1) ? s1 : (y == 2) ? s2 : s3;
  bf16_t*      d = (y == 0) ? dx : (y == 1) ? d1 : (y == 2) ? d2 : d3;
  const float4 v = *(const float4*)(s + i4);
  union { uint64_t u; bf16_t h[4]; } pk;
  pk.h[0] = (bf16_t)v.x; pk.h[1] = (bf16_t)v.y;
  pk.h[2] = (bf16_t)v.z; pk.h[3] = (bf16_t)v.w;
  *(uint64_t*)(d + i4) = pk.u;
}

// ---------------------------------------------------------------------------
// Async-staged bf16 GEMM (128x128, BK=64): QKV projections.
// mode 0: Q/K [B,H,S,64]; mode 1: V^T [B,H,64,S].
// ---------------------------------------------------------------------------
__global__ __launch_bounds__(256, 2) void gemm_qkv_a(
    const bf16_t* __restrict__ X,  const bf16_t* __restrict__ Wq,
    const bf16_t* __restrict__ Wk, const bf16_t* __restrict__ Wv,
    bf16_t* __restrict__ Q, bf16_t* __restrict__ K, bf16_t* __restrict__ V) {
  const int z = blockIdx.z;
  const bf16_t* W = (z == 0) ? Wq : (z == 1) ? Wk : Wv;
  bf16_t*       D = (z == 0) ? Q  : (z == 1) ? K  : V;
  const int mode = (z == 2) ? 1 : 0;

  __shared__ __align__(16) bf16_t As[128 * 64];
  __shared__ __align__(16) bf16_t Bs[128 * 64];

  const int tid  = threadIdx.x;
  const int lane = tid & 63;
  const int w    = tid >> 6;
  const int quad = lane >> 4;
  const int l15  = lane & 15;
  const int bm   = blockIdx.y * 128;
  const int bn   = blockIdx.x * 128;
  const int wm   = (w >> 1) * 64;
  const int wn   = (w & 1) * 64;
  const int sr   = lane >> 3;
  const int sc   = lane & 7;

  f32x4 acc[4][4] = {};

  for (int k0 = 0; k0 < 1024; k0 += 64) {
#pragma unroll
    for (int j = 0; j < 4; ++j) {
      const int r0 = w * 32 + j * 8;
      const int r  = r0 + sr;
      const int c  = sc ^ (r & 7);
      async_ld16(X + (size_t)(bm + r) * 1024 + k0 + c * 8, &As[r0 * 64]);
      async_ld16(W + (size_t)(bn + r) * 1024 + k0 + c * 8, &Bs[r0 * 64]);
    }
    __syncthreads();
#pragma unroll
    for (int kk = 0; kk < 64; kk += 32) {
      const int ck = (kk >> 3) + quad;
      bf16x8 aF[4], bF[4];
#pragma unroll
      for (int mt = 0; mt < 4; ++mt) {
        const int r = wm + mt * 16 + l15;
        aF[mt] = *(const bf16x8*)&As[r * 64 + (ck ^ (r & 7)) * 8];
      }
#pragma unroll
      for (int nt = 0; nt < 4; ++nt) {
        const int r = wn + nt * 16 + l15;
        bF[nt] = *(const bf16x8*)&Bs[r * 64 + (ck ^ (r & 7)) * 8];
      }
#pragma unroll
      for (int mt = 0; mt < 4; ++mt)
#pragma unroll
        for (int nt = 0; nt < 4; ++nt)
          acc[mt][nt] = MFMA16(aF[mt], bF[nt], acc[mt][nt]);
    }
    __syncthreads();
  }

#pragma unroll
  for (int mt = 0; mt < 4; ++mt) {
#pragma unroll
    for (int nt = 0; nt < 4; ++nt) {
      const int n  = bn + wn + nt * 16 + l15;
      const int mb = bm + wm + mt * 16 + quad * 4;
      const int h = n >> 6, hd = n & 63;
      if (mode == 0) {               // Q/K: [B,H,S,64]
#pragma unroll
        for (int r = 0; r < 4; ++r) {
          const int m = mb + r;
          const int b = m >> 11, s = m & 2047;
          D[(size_t)b * 2097152 + (size_t)h * 131072 + (size_t)s * 64 + hd] =
              (bf16_t)acc[mt][nt][r];
        }
      } else {                       // V^T: [B,H,64,S]; 4 consecutive tokens
        const int b = mb >> 11, s0 = mb & 2047;
        union { uint64_t u; bf16_t h4[4]; } pk;
#pragma unroll
        for (int r = 0; r < 4; ++r) pk.h4[r] = (bf16_t)acc[mt][nt][r];
        *(uint64_t*)(D + (size_t)b * 2097152 + (size_t)h * 131072 +
                     (size_t)hd * 2048 + s0) = pk.u;
      }
    }
  }
}

// ---------------------------------------------------------------------------
// gemm_out: 64x128 tile, BK=64, grid (8,64)=512 blocks (2/CU overlap).
// A = ctx bf16 (async LDS staging); B = Wo FP32 from d_in (register cvt ->
// swizzled LDS writes). out = ctx @ Wo^T + bo, FP32.
// ---------------------------------------------------------------------------
__global__ __launch_bounds__(256, 2) void gemm_out_m(
    const bf16_t* __restrict__ ctx, const float* __restrict__ Wo,
    float* __restrict__ out, const float* __restrict__ bo) {
  __shared__ __align__(16) bf16_t As[64 * 64];
  __shared__ __align__(16) bf16_t Bs[128 * 64];

  const int tid  = threadIdx.x;
  const int lane = tid & 63;
  const int w    = tid >> 6;
  const int quad = lane >> 4;
  const int l15  = lane & 15;
  const int bm   = blockIdx.y * 64;
  const int bn   = blockIdx.x * 128;
  const int wm   = (w >> 1) * 32;
  const int wn   = (w & 1) * 64;
  const int sr   = lane >> 3;
  const int sc   = lane & 7;
  const int srow = tid >> 3;        // 0..31
  const int schk = tid & 7;

  f32x4 acc[2][4] = {};

  for (int k0 = 0; k0 < 1024; k0 += 64) {
    // A: async bf16 staging (2 row-groups per wave)
#pragma unroll
    for (int j = 0; j < 2; ++j) {
      const int r0 = w * 16 + j * 8;
      const int r  = r0 + sr;
      const int c  = sc ^ (r & 7);
      async_ld16(ctx + (size_t)(bm + r) * 1024 + k0 + c * 8, &As[r0 * 64]);
    }
    // B: fp32 global -> regs (cvt) -> swizzled LDS (Bs free since loop-end barrier)
    u32x4 rb[4];
#pragma unroll
    for (int s2 = 0; s2 < 4; ++s2) {
      const int r = srow + s2 * 32;
      rb[s2] = ld8(Wo + (size_t)(bn + r) * 1024 + k0 + schk * 8);
    }
#pragma unroll
    for (int s2 = 0; s2 < 4; ++s2) {
      const int r = srow + s2 * 32;
      *(u32x4*)&Bs[r * 64 + ((schk ^ (r & 7)) * 8)] = rb[s2];
    }
    __syncthreads();    // drains async A (vmcnt) + B ds_writes (lgkmcnt)
#pragma unroll
    for (int kk = 0; kk < 64; kk += 32) {
      const int ck = (kk >> 3) + quad;
      bf16x8 aF[2], bF[4];
#pragma unroll
      for (int mt = 0; mt < 2; ++mt) {
        const int r = wm + mt * 16 + l15;
        aF[mt] = *(const bf16x8*)&As[r * 64 + (ck ^ (r & 7)) * 8];
      }
#pragma unroll
      for (int nt = 0; nt < 4; ++nt) {
        const int r = wn + nt * 16 + l15;
        bF[nt] = *(const bf16x8*)&Bs[r * 64 + (ck ^ (r & 7)) * 8];
      }
#pragma unroll
      for (int mt = 0; mt < 2; ++mt)
#pragma unroll
        for (int nt = 0; nt < 4; ++nt)
          acc[mt][nt] = MFMA16(aF[mt], bF[nt], acc[mt][nt]);
    }
    __syncthreads();    // all reads done before next staging overwrites
  }

#pragma unroll
  for (int mt = 0; mt < 2; ++mt) {
#pragma unroll
    for (int nt = 0; nt < 4; ++nt) {
      const int n  = bn + wn + nt * 16 + l15;
      const int mb = bm + wm + mt * 16 + quad * 4;
      const float bv = bo[n];
#pragma unroll
      for (int r = 0; r < 4; ++r)
        out[(size_t)(mb + r) * 1024 + n] = acc[mt][nt][r] + bv;
    }
  }
}

// ---------------------------------------------------------------------------
// Flash-style causal attention (R9 structure, halved tiles, 4 blocks/CU).
// Grid (32,16,2), 256 thr, launch_bounds(256,4).  Per block: 64 q-rows
// (16 per wave), KV tile 64.  Q,K: [B,H,S,64] bf16; V^T: [B,H,64,S] bf16.
// S^T = MFMA(A=K, B=Q): q=l15 (col), key=ntk*16+quad*4+r.  Softmax is
// register-local + shfl_xor(16,32); defer-max (R11-validated) skips the
// O-rescale unless the running max grows; setprio(1) around MFMA (T5).
// r64 remap: u=(z<<1)|(h>>3): {x, 31-x, (x+16)&31, (15-x)&31} -> every CU
// hosts exactly 66 block-iters.
// ---------------------------------------------------------------------------
__global__ __launch_bounds__(256, 4) void attn(
    const bf16_t* __restrict__ Qw, const bf16_t* __restrict__ Kw,
    const bf16_t* __restrict__ Vw, bf16_t* __restrict__ ctx) {
  constexpr int LDK = 72, LDV = 72, LDP = 72;
  __shared__ __align__(16) bf16_t Ks[64 * LDK];
  __shared__ __align__(16) bf16_t Vts[64 * LDV];
  __shared__ __align__(16) bf16_t Ps[64 * LDP];

  const int tid  = threadIdx.x;
  const int lane = tid & 63;
  const int w    = tid >> 6;
  const int quad = lane >> 4;
  const int l15  = lane & 15;
  const int h    = blockIdx.y;
  const int b    = blockIdx.z;
  const int x    = blockIdx.x;
  const int u    = (b << 1) | ((h >> 3) & 1);
  const int r64  = (u == 0) ? x
                 : (u == 1) ? (31 - x)
                 : (u == 2) ? ((x + 16) & 31)
                            : ((15 - x) & 31);
  const size_t bh = (size_t)(b * 16 + h) * (size_t)(2048 * 64);
  const bf16_t* Qh = Qw + bh;
  const bf16_t* Kh = Kw + bh;
  const bf16_t* Vh = Vw + bh;       // [64][2048]

  const int srl = lane >> 3, scl = lane & 7;

  // --- stage Q (64x64) through Ps region, read q-frags ---
  {
    const int srow = tid >> 3, sch = tid & 7;
    u32x4 rq[2];
#pragma unroll
    for (int s2 = 0; s2 < 2; ++s2)
      rq[s2] = *(const u32x4*)(Qh + (size_t)(r64 * 64 + srow + s2 * 32) * 64 + sch * 8);
#pragma unroll
    for (int s2 = 0; s2 < 2; ++s2)
      *(u32x4*)&Ps[(srow + s2 * 32) * LDP + sch * 8] = rq[s2];
  }
  __syncthreads();
  bf16x8 qF[2];
#pragma unroll
  for (int k2 = 0; k2 < 2; ++k2)
    qF[k2] = *(const bf16x8*)&Ps[(w * 16 + l15) * LDP + k2 * 32 + quad * 8];

  f32x4 O[4] = {};
  float mrow = -1e30f, lrow = 0.f;
  const float sc_log2 = 0.125f * 1.44269504088896340736f;  // 1/sqrt(64)*log2e
  const float DTHR = 44.0f;          // ~8/sc_log2 headroom (R11-validated)

  // --- preload kt=0 K/V tiles into registers ---
  u32x4 rk[2], rv[2];
#pragma unroll
  for (int j = 0; j < 2; ++j)
    rk[j] = *(const u32x4*)(Kh + (size_t)(w * 16 + j * 8 + srl) * 64 + scl * 8);
#pragma unroll
  for (int j = 0; j < 2; ++j)
    rv[j] = *(const u32x4*)(Vh + (size_t)(w * 16 + j * 8 + srl) * 2048 + scl * 8);

  for (int kt = 0; kt <= r64; ++kt) {
    __syncthreads();   // prior-iter LDS reads complete
#pragma unroll
    for (int j = 0; j < 2; ++j)
      *(u32x4*)&Ks[(w * 16 + j * 8 + srl) * LDK + scl * 8] = rk[j];
#pragma unroll
    for (int j = 0; j < 2; ++j)
      *(u32x4*)&Vts[(w * 16 + j * 8 + srl) * LDV + scl * 8] = rv[j];
    __syncthreads();

    // --- prefetch next K/V tile (overlaps all compute below) ---
    if (kt < r64) {
      const int kn = kt + 1;
#pragma unroll
      for (int j = 0; j < 2; ++j)
        rk[j] = *(const u32x4*)(Kh + (size_t)(kn * 64 + w * 16 + j * 8 + srl) * 64 + scl * 8);
#pragma unroll
      for (int j = 0; j < 2; ++j)
        rv[j] = *(const u32x4*)(Vh + (size_t)(w * 16 + j * 8 + srl) * 2048 + kn * 64 + scl * 8);
    }

    // --- S^T = K Q^T : q=l15 (col), key=ntk*16+quad*4+r ---
    f32x4 St[4] = {};
    __builtin_amdgcn_s_setprio(1);
#pragma unroll
    for (int ntk = 0; ntk < 4; ++ntk) {
      const int kr = ntk * 16 + l15;           // key row for A-frag
#pragma unroll
      for (int k2 = 0; k2 < 2; ++k2) {
        const bf16x8 kF = *(const bf16x8*)&Ks[kr * LDK + k2 * 32 + quad * 8];
        St[ntk] = MFMA16(kF, qF[k2], St[ntk]);
      }
    }
    __builtin_amdgcn_s_setprio(0);

    // --- diag mask only on the diagonal tile (wave-uniform branch) ---
    if (kt == r64) {
      const int ql = w * 16 + l15;
#pragma unroll
      for (int ntk = 0; ntk < 4; ++ntk)
#pragma unroll
        for (int r = 0; r < 4; ++r)
          if (ntk * 16 + quad * 4 + r > ql) St[ntk][r] = -1e30f;
    }

    // --- online softmax (register-local per q-column) ---
    float mx = -1e30f;
#pragma unroll
    for (int ntk = 0; ntk < 4; ++ntk)
#pragma unroll
      for (int r = 0; r < 4; ++r) mx = fmaxf(mx, St[ntk][r]);
    mx = fmaxf(mx, __shfl_xor(mx, 16));
    mx = fmaxf(mx, __shfl_xor(mx, 32));

    float alpha = 1.f;
    if (!__all(mx - mrow <= DTHR)) {   // defer-max: rescale rarely
      const float mnew = fmaxf(mrow, mx);
      alpha = exp2f((mrow - mnew) * sc_log2);
      mrow = mnew;
#pragma unroll
      for (int r = 0; r < 4; ++r) {
        const float a = __shfl(alpha, quad * 4 + r);
#pragma unroll
        for (int nt = 0; nt < 4; ++nt) O[nt][r] *= a;
      }
    }

    float rs = 0.f;
#pragma unroll
    for (int ntk = 0; ntk < 4; ++ntk) {
      union { uint64_t u64; bf16_t h4[4]; } pk;
#pragma unroll
      for (int r = 0; r < 4; ++r) {
        const float p = exp2f((St[ntk][r] - mrow) * sc_log2);
        rs += p;
        pk.h4[r] = (bf16_t)p;
      }
      *(uint64_t*)&Ps[(w * 16 + l15) * LDP + ntk * 16 + quad * 4] = pk.u64;
    }
    rs += __shfl_xor(rs, 16);
    rs += __shfl_xor(rs, 32);
    lrow = lrow * alpha + rs;

    // --- O += P V  (wave-private Ps rows; same-wave RAW, no barrier) ---
    __builtin_amdgcn_s_setprio(1);
#pragma unroll
    for (int kk = 0; kk < 64; kk += 32) {
      const int co = kk + quad * 8;
      const bf16x8 pF = *(const bf16x8*)&Ps[(w * 16 + l15) * LDP + co];
      bf16x8 vF[4];
#pragma unroll
      for (int nt = 0; nt < 4; ++nt)
        vF[nt] = *(const bf16x8*)&Vts[(nt * 16 + l15) * LDV + co];
#pragma unroll
      for (int nt = 0; nt < 4; ++nt)
        O[nt] = MFMA16(pF, vF[nt], O[nt]);
    }
    __builtin_amdgcn_s_setprio(0);
  }

  // --- epilogue: normalize (lrow broadcast from q-column lanes), store ---
#pragma unroll
  for (int r = 0; r < 4; ++r) {
    const float lr = __shfl(lrow, quad * 4 + r);
    const float iv = 1.f / lr;
    const int s = r64 * 64 + w * 16 + quad * 4 + r;
#pragma unroll
    for (int nt = 0; nt < 4; ++nt) {
      const int hd = nt * 16 + l15;
      ctx[(size_t)(b * 2048 + s) * 1024 + h * 64 + hd] =
          (bf16_t)(O[nt][r] * iv);
    }
  }
}

// ---------------------------------------------------------------------------
extern "C" void kernel_launch(void* const* d_in, const int* in_sizes, int n_in,
                              void* d_out, int out_size, void* d_ws, size_t ws_size,
                              hipStream_t stream) {
  const float* x  = (const float*)d_in[0];
  const float* Wq = (const float*)d_in[1];
  const float* Wk = (const float*)d_in[2];
  const float* Wv = (const float*)d_in[3];
  const float* Wo = (const float*)d_in[4];
  const float* bo = (const float*)d_in[5];

  bf16_t* ws   = (bf16_t*)d_ws;       // ws: exactly 32 MB used
  bf16_t* Qw   = ws;                  // 4M bf16 elems each
  bf16_t* Kw   = ws + 4194304;
  bf16_t* Vw   = ws + 8388608;        // [B,H,64,S]
  bf16_t* ctxw = ws + 12582912;

  bf16_t* dscr = (bf16_t*)d_out;      // d_out as bf16 scratch (14 of 16 MB)
  bf16_t* xb   = dscr;                // 8 MB
  bf16_t* Wqb  = dscr + 4194304;      // 2 MB each
  bf16_t* Wkb  = dscr + 5242880;
  bf16_t* Wvb  = dscr + 6291456;      // ends at 14 MB
  float*  out  = (float*)d_out;       // final fp32 output overwrites scratch

  dim3 blk(256);
  cvt_all<<<dim3(4096, 4), blk, 0, stream>>>(x, Wq, Wk, Wv, xb, Wqb, Wkb, Wvb);
  gemm_qkv_a<<<dim3(8, 32, 3), blk, 0, stream>>>(xb, Wqb, Wkb, Wvb, Qw, Kw, Vw);
  attn<<<dim3(32, 16, 2), blk, 0, stream>>>(Qw, Kw, Vw, ctxw);
  gemm_out_m<<<dim3(8, 64), blk, 0, stream>>>(ctxw, Wo, out, bo);
}

// Round 4
// 180.882 us; speedup vs baseline: 1.0531x; 1.0355x over previous
//
#include <hip/hip_runtime.h>
#include <stdint.h>

// ---------------------------------------------------------------------------
// MultiHeadAttention forward, MI355X/gfx950.  Round 13.
// fp32 I/O, bf16 MFMA compute. B=2 S=2048 D=1024 H=16 HD=64. M=4096.
// R13 vs R12 (187.3 us; attn 57.2 = strict max dispatch; other 3 kernels sum
// to ~125 us):
//  1) gemm_qkv_a: launch_bounds (256,2)->(256,3). 768 blocks = exactly 3/CU
//     -> whole grid co-resident, kills the 256-block tail (~1/3 of that
//     kernel's wall at half-machine utilization).
//  2) NEW cvt_wo: after attn, Wo fp32 -> bf16 into the then-dead Qw region
//     of ws (2 MB exact fit; stream-ordered, no race).  ~2-3 us.
//  3) gemm_out_m -> gemm_out_a: B (Wo) staged via global_load_lds bf16
//     (verbatim gemm_qkv pattern, 4 issues/wave) instead of per-iter fp32
//     loads + 64 register cvts + ds_writes (Wo was re-converted 64x).
//  attn: BYTE-IDENTICAL to R12 (57.2 us validated) for attribution.
// Pipeline: cvt_all -> gemm_qkv_a -> attn -> cvt_wo -> gemm_out_a.
// MFMA 16x16x32 layouts [m89-verified]:
//   A[m=l15][k=quad*8+j]; B[n=l15][k=quad*8+j]; C/D col=l15, row=quad*4+r.
// ---------------------------------------------------------------------------

typedef __bf16 bf16_t;
typedef __bf16 bf16x8 __attribute__((ext_vector_type(8)));
typedef float  f32x4  __attribute__((ext_vector_type(4)));
typedef uint32_t u32x4 __attribute__((ext_vector_type(4)));

#define MFMA16(A, B, C) __builtin_amdgcn_mfma_f32_16x16x32_bf16(A, B, C, 0, 0, 0)

__device__ __forceinline__ void async_ld16(const bf16_t* g, bf16_t* l) {
  __builtin_amdgcn_global_load_lds(
      (const __attribute__((address_space(1))) void*)g,
      (__attribute__((address_space(3))) void*)l, 16, 0, 0);
}

// --- fp32 -> bf16 converter: y=0 x (4096 blks); y=1..3 Wq/Wk/Wv (1024) -----
__global__ __launch_bounds__(256) void cvt_all(
    const float* __restrict__ sx, const float* __restrict__ s1,
    const float* __restrict__ s2, const float* __restrict__ s3,
    bf16_t* __restrict__ dx, bf16_t* __restrict__ d1,
    bf16_t* __restrict__ d2, bf16_t* __restrict__ d3) {
  const int y = blockIdx.y;
  if (y != 0 && blockIdx.x >= 1024) return;
  const int i4 = (blockIdx.x * 256 + threadIdx.x) * 4;
  const float* s = (y == 0) ? sx : (y == 1) ? s1 : (y == 2) ? s2 : s3;
  bf16_t*      d = (y == 0) ? dx : (y == 1) ? d1 : (y == 2) ? d2 : d3;
  const float4 v = *(const float4*)(s + i4);
  union { uint64_t u; bf16_t h[4]; } pk;
  pk.h[0] = (bf16_t)v.x; pk.h[1] = (bf16_t)v.y;
  pk.h[2] = (bf16_t)v.z; pk.h[3] = (bf16_t)v.w;
  *(uint64_t*)(d + i4) = pk.u;
}

// --- fp32 -> bf16, single tensor (Wo -> Qw region after attn) --------------
__global__ __launch_bounds__(256) void cvt_wo(
    const float* __restrict__ s, bf16_t* __restrict__ d) {
  const int i4 = (blockIdx.x * 256 + threadIdx.x) * 4;
  const float4 v = *(const float4*)(s + i4);
  union { uint64_t u; bf16_t h[4]; } pk;
  pk.h[0] = (bf16_t)v.x; pk.h[1] = (bf16_t)v.y;
  pk.h[2] = (bf16_t)v.z; pk.h[3] = (bf16_t)v.w;
  *(uint64_t*)(d + i4) = pk.u;
}

// ---------------------------------------------------------------------------
// Async-staged bf16 GEMM (128x128, BK=64): QKV projections.
// mode 0: Q/K [B,H,S,64]; mode 1: V^T [B,H,64,S].
// (256,3): 768 blocks = exactly 3/CU, fully co-resident (no tail).
// ---------------------------------------------------------------------------
__global__ __launch_bounds__(256, 3) void gemm_qkv_a(
    const bf16_t* __restrict__ X,  const bf16_t* __restrict__ Wq,
    const bf16_t* __restrict__ Wk, const bf16_t* __restrict__ Wv,
    bf16_t* __restrict__ Q, bf16_t* __restrict__ K, bf16_t* __restrict__ V) {
  const int z = blockIdx.z;
  const bf16_t* W = (z == 0) ? Wq : (z == 1) ? Wk : Wv;
  bf16_t*       D = (z == 0) ? Q  : (z == 1) ? K  : V;
  const int mode = (z == 2) ? 1 : 0;

  __shared__ __align__(16) bf16_t As[128 * 64];
  __shared__ __align__(16) bf16_t Bs[128 * 64];

  const int tid  = threadIdx.x;
  const int lane = tid & 63;
  const int w    = tid >> 6;
  const int quad = lane >> 4;
  const int l15  = lane & 15;
  const int bm   = blockIdx.y * 128;
  const int bn   = blockIdx.x * 128;
  const int wm   = (w >> 1) * 64;
  const int wn   = (w & 1) * 64;
  const int sr   = lane >> 3;
  const int sc   = lane & 7;

  f32x4 acc[4][4] = {};

  for (int k0 = 0; k0 < 1024; k0 += 64) {
#pragma unroll
    for (int j = 0; j < 4; ++j) {
      const int r0 = w * 32 + j * 8;
      const int r  = r0 + sr;
      const int c  = sc ^ (r & 7);
      async_ld16(X + (size_t)(bm + r) * 1024 + k0 + c * 8, &As[r0 * 64]);
      async_ld16(W + (size_t)(bn + r) * 1024 + k0 + c * 8, &Bs[r0 * 64]);
    }
    __syncthreads();
#pragma unroll
    for (int kk = 0; kk < 64; kk += 32) {
      const int ck = (kk >> 3) + quad;
      bf16x8 aF[4], bF[4];
#pragma unroll
      for (int mt = 0; mt < 4; ++mt) {
        const int r = wm + mt * 16 + l15;
        aF[mt] = *(const bf16x8*)&As[r * 64 + (ck ^ (r & 7)) * 8];
      }
#pragma unroll
      for (int nt = 0; nt < 4; ++nt) {
        const int r = wn + nt * 16 + l15;
        bF[nt] = *(const bf16x8*)&Bs[r * 64 + (ck ^ (r & 7)) * 8];
      }
#pragma unroll
      for (int mt = 0; mt < 4; ++mt)
#pragma unroll
        for (int nt = 0; nt < 4; ++nt)
          acc[mt][nt] = MFMA16(aF[mt], bF[nt], acc[mt][nt]);
    }
    __syncthreads();
  }

#pragma unroll
  for (int mt = 0; mt < 4; ++mt) {
#pragma unroll
    for (int nt = 0; nt < 4; ++nt) {
      const int n  = bn + wn + nt * 16 + l15;
      const int mb = bm + wm + mt * 16 + quad * 4;
      const int h = n >> 6, hd = n & 63;
      if (mode == 0) {               // Q/K: [B,H,S,64]
#pragma unroll
        for (int r = 0; r < 4; ++r) {
          const int m = mb + r;
          const int b = m >> 11, s = m & 2047;
          D[(size_t)b * 2097152 + (size_t)h * 131072 + (size_t)s * 64 + hd] =
              (bf16_t)acc[mt][nt][r];
        }
      } else {                       // V^T: [B,H,64,S]; 4 consecutive tokens
        const int b = mb >> 11, s0 = mb & 2047;
        union { uint64_t u; bf16_t h4[4]; } pk;
#pragma unroll
        for (int r = 0; r < 4; ++r) pk.h4[r] = (bf16_t)acc[mt][nt][r];
        *(uint64_t*)(D + (size_t)b * 2097152 + (size_t)h * 131072 +
                     (size_t)hd * 2048 + s0) = pk.u;
      }
    }
  }
}

// ---------------------------------------------------------------------------
// gemm_out_a: 64x128 tile, BK=64, grid (8,64)=512 blocks (2/CU, no tail).
// A = ctx bf16, B = Wo bf16 (pre-converted by cvt_wo into Qw region): BOTH
// staged via global_load_lds (gemm_qkv pattern).  out = ctx @ Wo^T + bo.
// ---------------------------------------------------------------------------
__global__ __launch_bounds__(256, 2) void gemm_out_a(
    const bf16_t* __restrict__ ctx, const bf16_t* __restrict__ Wob,
    float* __restrict__ out, const float* __restrict__ bo) {
  __shared__ __align__(16) bf16_t As[64 * 64];
  __shared__ __align__(16) bf16_t Bs[128 * 64];

  const int tid  = threadIdx.x;
  const int lane = tid & 63;
  const int w    = tid >> 6;
  const int quad = lane >> 4;
  const int l15  = lane & 15;
  const int bm   = blockIdx.y * 64;
  const int bn   = blockIdx.x * 128;
  const int wm   = (w >> 1) * 32;
  const int wn   = (w & 1) * 64;
  const int sr   = lane >> 3;
  const int sc   = lane & 7;

  f32x4 acc[2][4] = {};

  for (int k0 = 0; k0 < 1024; k0 += 64) {
    // A: async bf16 staging (2 row-groups per wave)
#pragma unroll
    for (int j = 0; j < 2; ++j) {
      const int r0 = w * 16 + j * 8;
      const int r  = r0 + sr;
      const int c  = sc ^ (r & 7);
      async_ld16(ctx + (size_t)(bm + r) * 1024 + k0 + c * 8, &As[r0 * 64]);
    }
    // B: async bf16 staging (4 row-groups per wave)
#pragma unroll
    for (int j = 0; j < 4; ++j) {
      const int r0 = w * 32 + j * 8;
      const int r  = r0 + sr;
      const int c  = sc ^ (r & 7);
      async_ld16(Wob + (size_t)(bn + r) * 1024 + k0 + c * 8, &Bs[r0 * 64]);
    }
    __syncthreads();    // drains async A+B (vmcnt)
#pragma unroll
    for (int kk = 0; kk < 64; kk += 32) {
      const int ck = (kk >> 3) + quad;
      bf16x8 aF[2], bF[4];
#pragma unroll
      for (int mt = 0; mt < 2; ++mt) {
        const int r = wm + mt * 16 + l15;
        aF[mt] = *(const bf16x8*)&As[r * 64 + (ck ^ (r & 7)) * 8];
      }
#pragma unroll
      for (int nt = 0; nt < 4; ++nt) {
        const int r = wn + nt * 16 + l15;
        bF[nt] = *(const bf16x8*)&Bs[r * 64 + (ck ^ (r & 7)) * 8];
      }
#pragma unroll
      for (int mt = 0; mt < 2; ++mt)
#pragma unroll
        for (int nt = 0; nt < 4; ++nt)
          acc[mt][nt] = MFMA16(aF[mt], bF[nt], acc[mt][nt]);
    }
    __syncthreads();    // all reads done before next staging overwrites
  }

#pragma unroll
  for (int mt = 0; mt < 2; ++mt) {
#pragma unroll
    for (int nt = 0; nt < 4; ++nt) {
      const int n  = bn + wn + nt * 16 + l15;
      const int mb = bm + wm + mt * 16 + quad * 4;
      const float bv = bo[n];
#pragma unroll
      for (int r = 0; r < 4; ++r)
        out[(size_t)(mb + r) * 1024 + n] = acc[mt][nt][r] + bv;
    }
  }
}

// ---------------------------------------------------------------------------
// Flash-style causal attention (R12, byte-identical; 57.2 us validated).
// Grid (32,16,2), 256 thr, launch_bounds(256,4).  Per block: 64 q-rows
// (16 per wave), KV tile 64.  Q,K: [B,H,S,64] bf16; V^T: [B,H,64,S] bf16.
// S^T = MFMA(A=K, B=Q): q=l15 (col), key=ntk*16+quad*4+r.  Softmax is
// register-local + shfl_xor(16,32); defer-max skips the O-rescale unless
// the running max grows; setprio(1) around MFMA (T5).
// r64 remap: u=(z<<1)|(h>>3): {x, 31-x, (x+16)&31, (15-x)&31} -> every CU
// hosts exactly 66 block-iters.
// ---------------------------------------------------------------------------
__global__ __launch_bounds__(256, 4) void attn(
    const bf16_t* __restrict__ Qw, const bf16_t* __restrict__ Kw,
    const bf16_t* __restrict__ Vw, bf16_t* __restrict__ ctx) {
  constexpr int LDK = 72, LDV = 72, LDP = 72;
  __shared__ __align__(16) bf16_t Ks[64 * LDK];
  __shared__ __align__(16) bf16_t Vts[64 * LDV];
  __shared__ __align__(16) bf16_t Ps[64 * LDP];

  const int tid  = threadIdx.x;
  const int lane = tid & 63;
  const int w    = tid >> 6;
  const int quad = lane >> 4;
  const int l15  = lane & 15;
  const int h    = blockIdx.y;
  const int b    = blockIdx.z;
  const int x    = blockIdx.x;
  const int u    = (b << 1) | ((h >> 3) & 1);
  const int r64  = (u == 0) ? x
                 : (u == 1) ? (31 - x)
                 : (u == 2) ? ((x + 16) & 31)
                            : ((15 - x) & 31);
  const size_t bh = (size_t)(b * 16 + h) * (size_t)(2048 * 64);
  const bf16_t* Qh = Qw + bh;
  const bf16_t* Kh = Kw + bh;
  const bf16_t* Vh = Vw + bh;       // [64][2048]

  const int srl = lane >> 3, scl = lane & 7;

  // --- stage Q (64x64) through Ps region, read q-frags ---
  {
    const int srow = tid >> 3, sch = tid & 7;
    u32x4 rq[2];
#pragma unroll
    for (int s2 = 0; s2 < 2; ++s2)
      rq[s2] = *(const u32x4*)(Qh + (size_t)(r64 * 64 + srow + s2 * 32) * 64 + sch * 8);
#pragma unroll
    for (int s2 = 0; s2 < 2; ++s2)
      *(u32x4*)&Ps[(srow + s2 * 32) * LDP + sch * 8] = rq[s2];
  }
  __syncthreads();
  bf16x8 qF[2];
#pragma unroll
  for (int k2 = 0; k2 < 2; ++k2)
    qF[k2] = *(const bf16x8*)&Ps[(w * 16 + l15) * LDP + k2 * 32 + quad * 8];

  f32x4 O[4] = {};
  float mrow = -1e30f, lrow = 0.f;
  const float sc_log2 = 0.125f * 1.44269504088896340736f;  // 1/sqrt(64)*log2e
  const float DTHR = 44.0f;          // ~8/sc_log2 headroom (R11-validated)

  // --- preload kt=0 K/V tiles into registers ---
  u32x4 rk[2], rv[2];
#pragma unroll
  for (int j = 0; j < 2; ++j)
    rk[j] = *(const u32x4*)(Kh + (size_t)(w * 16 + j * 8 + srl) * 64 + scl * 8);
#pragma unroll
  for (int j = 0; j < 2; ++j)
    rv[j] = *(const u32x4*)(Vh + (size_t)(w * 16 + j * 8 + srl) * 2048 + scl * 8);

  for (int kt = 0; kt <= r64; ++kt) {
    __syncthreads();   // prior-iter LDS reads complete
#pragma unroll
    for (int j = 0; j < 2; ++j)
      *(u32x4*)&Ks[(w * 16 + j * 8 + srl) * LDK + scl * 8] = rk[j];
#pragma unroll
    for (int j = 0; j < 2; ++j)
      *(u32x4*)&Vts[(w * 16 + j * 8 + srl) * LDV + scl * 8] = rv[j];
    __syncthreads();

    // --- prefetch next K/V tile (overlaps all compute below) ---
    if (kt < r64) {
      const int kn = kt + 1;
#pragma unroll
      for (int j = 0; j < 2; ++j)
        rk[j] = *(const u32x4*)(Kh + (size_t)(kn * 64 + w * 16 + j * 8 + srl) * 64 + scl * 8);
#pragma unroll
      for (int j = 0; j < 2; ++j)
        rv[j] = *(const u32x4*)(Vh + (size_t)(w * 16 + j * 8 + srl) * 2048 + kn * 64 + scl * 8);
    }

    // --- S^T = K Q^T : q=l15 (col), key=ntk*16+quad*4+r ---
    f32x4 St[4] = {};
    __builtin_amdgcn_s_setprio(1);
#pragma unroll
    for (int ntk = 0; ntk < 4; ++ntk) {
      const int kr = ntk * 16 + l15;           // key row for A-frag
#pragma unroll
      for (int k2 = 0; k2 < 2; ++k2) {
        const bf16x8 kF = *(const bf16x8*)&Ks[kr * LDK + k2 * 32 + quad * 8];
        St[ntk] = MFMA16(kF, qF[k2], St[ntk]);
      }
    }
    __builtin_amdgcn_s_setprio(0);

    // --- diag mask only on the diagonal tile (wave-uniform branch) ---
    if (kt == r64) {
      const int ql = w * 16 + l15;
#pragma unroll
      for (int ntk = 0; ntk < 4; ++ntk)
#pragma unroll
        for (int r = 0; r < 4; ++r)
          if (ntk * 16 + quad * 4 + r > ql) St[ntk][r] = -1e30f;
    }

    // --- online softmax (register-local per q-column) ---
    float mx = -1e30f;
#pragma unroll
    for (int ntk = 0; ntk < 4; ++ntk)
#pragma unroll
      for (int r = 0; r < 4; ++r) mx = fmaxf(mx, St[ntk][r]);
    mx = fmaxf(mx, __shfl_xor(mx, 16));
    mx = fmaxf(mx, __shfl_xor(mx, 32));

    float alpha = 1.f;
    if (!__all(mx - mrow <= DTHR)) {   // defer-max: rescale rarely
      const float mnew = fmaxf(mrow, mx);
      alpha = exp2f((mrow - mnew) * sc_log2);
      mrow = mnew;
#pragma unroll
      for (int r = 0; r < 4; ++r) {
        const float a = __shfl(alpha, quad * 4 + r);
#pragma unroll
        for (int nt = 0; nt < 4; ++nt) O[nt][r] *= a;
      }
    }

    float rs = 0.f;
#pragma unroll
    for (int ntk = 0; ntk < 4; ++ntk) {
      union { uint64_t u64; bf16_t h4[4]; } pk;
#pragma unroll
      for (int r = 0; r < 4; ++r) {
        const float p = exp2f((St[ntk][r] - mrow) * sc_log2);
        rs += p;
        pk.h4[r] = (bf16_t)p;
      }
      *(uint64_t*)&Ps[(w * 16 + l15) * LDP + ntk * 16 + quad * 4] = pk.u64;
    }
    rs += __shfl_xor(rs, 16);
    rs += __shfl_xor(rs, 32);
    lrow = lrow * alpha + rs;

    // --- O += P V  (wave-private Ps rows; same-wave RAW, no barrier) ---
    __builtin_amdgcn_s_setprio(1);
#pragma unroll
    for (int kk = 0; kk < 64; kk += 32) {
      const int co = kk + quad * 8;
      const bf16x8 pF = *(const bf16x8*)&Ps[(w * 16 + l15) * LDP + co];
      bf16x8 vF[4];
#pragma unroll
      for (int nt = 0; nt < 4; ++nt)
        vF[nt] = *(const bf16x8*)&Vts[(nt * 16 + l15) * LDV + co];
#pragma unroll
      for (int nt = 0; nt < 4; ++nt)
        O[nt] = MFMA16(pF, vF[nt], O[nt]);
    }
    __builtin_amdgcn_s_setprio(0);
  }

  // --- epilogue: normalize (lrow broadcast from q-column lanes), store ---
#pragma unroll
  for (int r = 0; r < 4; ++r) {
    const float lr = __shfl(lrow, quad * 4 + r);
    const float iv = 1.f / lr;
    const int s = r64 * 64 + w * 16 + quad * 4 + r;
#pragma unroll
    for (int nt = 0; nt < 4; ++nt) {
      const int hd = nt * 16 + l15;
      ctx[(size_t)(b * 2048 + s) * 1024 + h * 64 + hd] =
          (bf16_t)(O[nt][r] * iv);
    }
  }
}

// ---------------------------------------------------------------------------
extern "C" void kernel_launch(void* const* d_in, const int* in_sizes, int n_in,
                              void* d_out, int out_size, void* d_ws, size_t ws_size,
                              hipStream_t stream) {
  const float* x  = (const float*)d_in[0];
  const float* Wq = (const float*)d_in[1];
  const float* Wk = (const float*)d_in[2];
  const float* Wv = (const float*)d_in[3];
  const float* Wo = (const float*)d_in[4];
  const float* bo = (const float*)d_in[5];

  bf16_t* ws   = (bf16_t*)d_ws;       // ws: exactly 32 MB used
  bf16_t* Qw   = ws;                  // 4M bf16 elems each
  bf16_t* Kw   = ws + 4194304;
  bf16_t* Vw   = ws + 8388608;        // [B,H,64,S]
  bf16_t* ctxw = ws + 12582912;
  bf16_t* Wob  = Qw;                  // Qw dead after attn; reuse for Wo bf16

  bf16_t* dscr = (bf16_t*)d_out;      // d_out as bf16 scratch (14 of 16 MB)
  bf16_t* xb   = dscr;                // 8 MB
  bf16_t* Wqb  = dscr + 4194304;      // 2 MB each
  bf16_t* Wkb  = dscr + 5242880;
  bf16_t* Wvb  = dscr + 6291456;      // ends at 14 MB
  float*  out  = (float*)d_out;       // final fp32 output overwrites scratch

  dim3 blk(256);
  cvt_all<<<dim3(4096, 4), blk, 0, stream>>>(x, Wq, Wk, Wv, xb, Wqb, Wkb, Wvb);
  gemm_qkv_a<<<dim3(8, 32, 3), blk, 0, stream>>>(xb, Wqb, Wkb, Wvb, Qw, Kw, Vw);
  attn<<<dim3(32, 16, 2), blk, 0, stream>>>(Qw, Kw, Vw, ctxw);
  cvt_wo<<<dim3(1024), blk, 0, stream>>>(Wo, Wob);
  gemm_out_a<<<dim3(8, 64), blk, 0, stream>>>(ctxw, Wob, out, bo);
}